// Round 3
// baseline (318.463 us; speedup 1.0000x reference)
//
#include <hip/hip_runtime.h>

// Adder: base-10 digit addition with carry-lookahead, vectorized 16B/lane.
// Layout: (B=524288, S=64) fp32 digits, index 0 = MSB, index 63 = LSB.
// One wave (64 lanes) covers 4 rows: row r = lanes 16r..16r+15, lane j-of-row
// holds digits 4j..4j+3 (float4). Carry chain solved in closed form:
//   digit level : g=(s>=10), p=(s==9)  (mutually exclusive, s in 0..18 exact)
//   lane level  : 4-bit lookahead C4=(PG+G)^PG^G; bit4 = group-generate,
//                 group-propagate = (p4==0xF)
//   row level   : one __ballot pair for all 4 rows; 16-bit lookahead per row
//                 (bit-reversed into LSB-first space; overflow past bit 15
//                 drops the row's top carry, matching the reference).
// All values are small exact integers in fp32, so float compares are exact.

typedef float f32x4 __attribute__((ext_vector_type(4)));  // native vector:
// HIP_vector_type float4 is a class and is rejected by nontemporal builtins.

__global__ __launch_bounds__(256) void adder_kernel(
    const float* __restrict__ a,
    const float* __restrict__ b,
    float* __restrict__ out)
{
    const int lane = (int)(threadIdx.x & 63);
    const long long wave = (long long)blockIdx.x * 4 + (threadIdx.x >> 6);

    // each wave: 4 rows = 256 floats = 1024 B per array, fully coalesced
    const long long base = wave * 256 + 4 * lane;

    const f32x4 av = *(const f32x4*)(a + base);
    const f32x4 bv = *(const f32x4*)(b + base);

    const float s0 = av.x + bv.x;   // most significant of this lane's group
    const float s1 = av.y + bv.y;
    const float s2 = av.z + bv.z;
    const float s3 = av.w + bv.w;   // least significant

    // 4-bit masks, LSB-first within the group: bit0 <-> s3 ... bit3 <-> s0
    const unsigned g4 = (unsigned)(s3 >= 10.0f)
                      | ((unsigned)(s2 >= 10.0f) << 1)
                      | ((unsigned)(s1 >= 10.0f) << 2)
                      | ((unsigned)(s0 >= 10.0f) << 3);
    const unsigned p4 = (unsigned)(s3 == 9.0f)
                      | ((unsigned)(s2 == 9.0f) << 1)
                      | ((unsigned)(s1 == 9.0f) << 2)
                      | ((unsigned)(s0 == 9.0f) << 3);
    const unsigned pg4 = p4 | g4;
    const unsigned c4  = (pg4 + g4) ^ pg4 ^ g4;   // carries; bit4 = group gen
    const bool Ggrp = (c4 >> 4) & 1u;
    const bool Pgrp = (p4 == 0xFu);

    // group G/P for all 4 rows of this wave in one ballot pair
    const unsigned long long Gl = __ballot(Ggrp);
    const unsigned long long Pl = __ballot(Pgrp);

    const int r = lane >> 4;   // which row of the wave
    const int j = lane & 15;   // group index in row, j=0 most significant

    unsigned Gr = (unsigned)((Gl >> (16 * r)) & 0xFFFFull);
    unsigned Pr = (unsigned)((Pl >> (16 * r)) & 0xFFFFull);
    // lane j <-> LSB-first position k = 15-j : 16-bit reverse
    Gr = __brev(Gr) >> 16;
    Pr = __brev(Pr) >> 16;
    const unsigned PGr = Pr | Gr;
    const unsigned Cr  = (PGr + Gr) ^ PGr ^ Gr;   // carry-in per group position

    const float cin = (float)((Cr >> (15 - j)) & 1u);

    // serial ripple through the lane's 4 digits, LSB (s3) first
    float u, c;
    f32x4 d;
    u = s3 + cin; c = (u >= 10.0f) ? 1.0f : 0.0f; d.w = u - 10.0f * c;
    u = s2 + c;   c = (u >= 10.0f) ? 1.0f : 0.0f; d.z = u - 10.0f * c;
    u = s1 + c;   c = (u >= 10.0f) ? 1.0f : 0.0f; d.y = u - 10.0f * c;
    u = s0 + c;   c = (u >= 10.0f) ? 1.0f : 0.0f; d.x = u - 10.0f * c;

    // write-once output: nontemporal store keeps L2/L3 for the input stream
    __builtin_nontemporal_store(d, (f32x4*)(out + base));
}

extern "C" void kernel_launch(void* const* d_in, const int* in_sizes, int n_in,
                              void* d_out, int out_size, void* d_ws, size_t ws_size,
                              hipStream_t stream) {
    const float* a = (const float*)d_in[0];
    const float* b = (const float*)d_in[1];
    float* out = (float*)d_out;

    // 524288 rows x 64 digits; 4 rows/wave, 4 waves/block -> 16 rows/block
    const long long n_rows = (long long)in_sizes[0] / 64;
    const int blocks = (int)(n_rows / 16);   // 32768, divides exactly
    adder_kernel<<<blocks, 256, 0, stream>>>(a, b, out);
}